// Round 7
// baseline (151.909 us; speedup 1.0000x reference)
//
#include <hip/hip_runtime.h>
#include <math.h>

#define NRAY2 4096
#define NSAMP 64
#define PHD 192
#define PLANE (PHD*PHD)          // 36864
constexpr float STEP = 1.0f / 63.0f;

struct Mats { float crd[16]; float drv[16]; };

// ---------------- host-side constant matrices (replicates numpy fp64 math) ---
static void mat_mul4(const double* A, const double* B, double* C) {
    for (int i = 0; i < 4; ++i)
        for (int j = 0; j < 4; ++j) {
            double s = 0.0;
            for (int k = 0; k < 4; ++k) s += A[i*4+k] * B[k*4+j];
            C[i*4+j] = s;
        }
}

static void build_mats(Mats& M) {
    const double tx = 0.1, ty = 0.05, tz = 0.02;
    const double cx = 0.5, cy = 0.5, cz = 0.5;
    auto ry = [](double t, double* m) {
        double c = cos(t), s = sin(t);
        double v[16] = {1,0,0,0, 0,c,-s,0, 0,s,c,0, 0,0,0,1};
        for (int i = 0; i < 16; ++i) m[i] = v[i];
    };
    auto rx = [](double t, double* m) {
        double c = cos(t), s = sin(t);
        double v[16] = {c,0,-s,0, 0,1,0,0, s,0,c,0, 0,0,0,1};
        for (int i = 0; i < 16; ++i) m[i] = v[i];
    };
    auto rz = [](double t, double* m) {
        double c = cos(t), s = sin(t);
        double v[16] = {c,-s,0,0, s,c,0,0, 0,0,1,0, 0,0,0,1};
        for (int i = 0; i < 16; ++i) m[i] = v[i];
    };
    double RY[16], RY_[16], RX[16], RX_[16], RZ[16], RZ_[16];
    ry(-ty, RY); ry(ty, RY_);
    rx(tx, RX);  rx(-tx, RX_);
    rz(-tz, RZ); rz(tz, RZ_);
    double S1[16] = {1,0,0,0, 0,1,0,0, 0,0,1,0, -cx,-cy,-cz,1};
    double S2[16] = {1,0,0,0, 0,1,0,0, 0,0,1,0,  cx, cy, cz,1};
    double t1[16], t2[16], t3[16], Mc[16], Md[16];
    mat_mul4(S1, RZ, t1);
    mat_mul4(t1, RY, t2);
    mat_mul4(t2, RX, t3);
    mat_mul4(t3, S2, Mc);
    mat_mul4(RX_, RY_, t1);
    mat_mul4(t1, RZ_, Md);
    for (int i = 0; i < 16; ++i) { M.crd[i] = (float)Mc[i]; M.drv[i] = (float)Md[i]; }
}

// One butterfly level applied to all 8 values (chains overlap).
template<int CTRL>
__device__ __forceinline__ void dpp_level8(float* v) {
    int t[8];
    #pragma unroll
    for (int i = 0; i < 8; ++i)
        t[i] = __builtin_amdgcn_update_dpp(0, __float_as_int(v[i]), CTRL, 0xF, 0xF, true);
    #pragma unroll
    for (int i = 0; i < 8; ++i) v[i] += __int_as_float(t[i]);
}

// 16-lane allreduce of 8 values: 4 pure-DPP row_ror levels, no LDS waits.
__device__ __forceinline__ void red8_16(float* v) {
    dpp_level8<0x121>(v);   // row_ror:1
    dpp_level8<0x122>(v);   // row_ror:2
    dpp_level8<0x124>(v);   // row_ror:4
    dpp_level8<0x128>(v);   // row_ror:8
}

// ---------------- kernel 1: ray tracing -------------------------------------
// 16 lanes per ray, 2 neighbors per lane. One-step-ahead RI prefetch;
// s-loop unrolled 3x so 2/3 of load->use pairs sit in one basic block where
// the waitcnt pass emits precise vmcnt(N) instead of the conservative
// vmcnt(0) it uses for loop-carried values (the R6 stall).
__global__ __launch_bounds__(256) void ray_trace_kernel(
    const float* __restrict__ RI,       // (64^3, 2) interleaved [A, sig]
    const float* __restrict__ RayInit,  // (4096, 5)
    float* __restrict__ meshXT,         // (64, 4096)  stores 2X-1
    float* __restrict__ meshYT,         // (64, 4096)  stores 2Y-1
    Mats M)
{
    const int tid = threadIdx.x;
    const int nb  = tid & 15;                        // lane within 16-row
    const int ray = blockIdx.x * 16 + (tid >> 4);
    const bool act2 = nb < 11;                       // second neighbor active

    const int n1 = nb, n2 = nb + 16;
    const float xr1 = (float)((n1/3)%3 - 1), yr1 = (float)(n1/9 - 1), zr1 = (float)(n1%3 - 1);
    const float xr2 = (float)((n2/3)%3 - 1), yr2 = (float)(n2/9 - 1), zr2 = (float)(n2%3 - 1);

    float X  = RayInit[ray*5 + 0];
    float dX = RayInit[ray*5 + 1];
    float Y  = RayInit[ray*5 + 2];
    float dY = RayInit[ray*5 + 3];
    float z  = RayInit[ray*5 + 4];

    if (nb == 0) meshXT[ray] = X*2.0f - 1.0f;
    if (nb == 1) meshYT[ray] = Y*2.0f - 1.0f;

    auto prep = [&](float pX, float pY, float pz,
                    float& ox, float& oy, float& oz,
                    float& X1, float& Y1, float& Z1,
                    float& X2, float& Y2, float& Z2,
                    float2& r1, float2& r2) {
        float x  = pY*M.crd[1] + pX*M.crd[5] + pz*M.crd[9]  + M.crd[13];
        float y  = pY*M.crd[0] + pX*M.crd[4] + pz*M.crd[8]  + M.crd[12];
        float zz = pY*M.crd[2] + pX*M.crd[6] + pz*M.crd[10] + M.crd[14];
        float rx_ = rintf(x*64.0f), ry_ = rintf(y*64.0f), rz_ = rintf(zz*64.0f);
        X1 = __builtin_amdgcn_fmed3f(rx_ + xr1, 0.0f, 63.0f);
        Y1 = __builtin_amdgcn_fmed3f(ry_ + yr1, 0.0f, 63.0f);
        Z1 = __builtin_amdgcn_fmed3f(rz_ + zr1, 0.0f, 63.0f);
        X2 = __builtin_amdgcn_fmed3f(rx_ + xr2, 0.0f, 63.0f);
        Y2 = __builtin_amdgcn_fmed3f(ry_ + yr2, 0.0f, 63.0f);
        Z2 = __builtin_amdgcn_fmed3f(rz_ + zr2, 0.0f, 63.0f);
        int l1 = (int)(Y1*4096.0f + X1*64.0f + Z1);   // exact in fp32
        int l2 = (int)(Y2*4096.0f + X2*64.0f + Z2);
        r1 = ((const float2*)RI)[l1];
        r2 = ((const float2*)RI)[l2];
        ox = x; oy = y; oz = zz;
    };

    float cx_, cy_, cz_, Xn1, Yn1, Zn1, Xn2, Yn2, Zn2;
    float2 ri1, ri2;
    prep(X, Y, z, cx_, cy_, cz_, Xn1, Yn1, Zn1, Xn2, Yn2, Zn2, ri1, ri2);

    // v_exp_f32 computes 2^x: fold -0.5*log2(e) into the Gaussian constant.
    const float C = -0.72134752044448169f;   // -0.5 * log2(e)

    #pragma unroll 3
    for (int s = 1; s < NSAMP; ++s) {
        // one-step-ahead prefetch (uses only pre-reduction state)
        float nX = X + dX*STEP, nY = Y + dY*STEP, nz = z + STEP;
        float ncx, ncy, ncz, mX1, mY1, mZ1, mX2, mY2, mZ2;
        float2 ri1n, ri2n;
        prep(nX, nY, nz, ncx, ncy, ncz, mX1, mY1, mZ1, mX2, mY2, mZ2, ri1n, ri2n);

        // neighbor 1 contribution
        float dx1 = Xn1*(1.0f/63.0f) - cx_;
        float dy1 = Yn1*(1.0f/63.0f) - cy_;
        float dz1 = Zn1*(1.0f/63.0f) - cz_;
        float is1 = __builtin_amdgcn_rcpf(ri1.y * ri1.y);
        float d21 = dx1*dx1 + dy1*dy1 + dz1*dz1;
        float e1  = __builtin_amdgcn_exp2f(d21 * is1 * C) + 2e-7f;
        float g1x = dx1*is1, g1y = dy1*is1, g1z = dz1*is1;
        float nu1 = e1 * ri1.x;

        // neighbor 2 contribution (zeroed when inactive)
        float dx2 = Xn2*(1.0f/63.0f) - cx_;
        float dy2 = Yn2*(1.0f/63.0f) - cy_;
        float dz2 = Zn2*(1.0f/63.0f) - cz_;
        float is2 = __builtin_amdgcn_rcpf(ri2.y * ri2.y);
        float d22 = dx2*dx2 + dy2*dy2 + dz2*dz2;
        float e2  = __builtin_amdgcn_exp2f(d22 * is2 * C) + 2e-7f;
        if (!act2) e2 = 0.0f;
        float g2x = dx2*is2, g2y = dy2*is2, g2z = dz2*is2;
        float nu2 = e2 * ri2.x;

        float v[8] = { e1 + e2,
                       nu1 + nu2,
                       nu1*g1x + nu2*g2x,
                       nu1*g1y + nu2*g2y,
                       nu1*g1z + nu2*g2z,
                       e1*g1x + e2*g2x,
                       e1*g1y + e2*g2y,
                       e1*g1z + e2*g2z };
        red8_16(v);
        float ni  = v[0], nuA = v[1];
        float sx  = v[2], sy  = v[3], sz  = v[4];
        float sdx = v[5], sdy = v[6], sdz = v[7];

        float r   = __builtin_amdgcn_rcpf(ni);
        float rn  = ni * __builtin_amdgcn_rcpf(nuA);   // 1/n = norm/nu_s
        float in2 = r * r;
        float gx_ = (ni*sx - nuA*sdx) * in2;
        float gy_ = (ni*sy - nuA*sdy) * in2;
        float gz_ = (ni*sz - nuA*sdz) * in2;

        float dndx = gy_*M.drv[1] + gx_*M.drv[5] + gz_*M.drv[9]  + M.drv[13];
        float dndy = gy_*M.drv[0] + gx_*M.drv[4] + gz_*M.drv[8]  + M.drv[12];
        float dndz = gy_*M.drv[2] + gx_*M.drv[6] + gz_*M.drv[10] + M.drv[14];

        float dX2 = (dndx - dndz*dX) * (1.0f + dX*dX) * rn;
        float dY2 = (dndy - dndz*dY) * (1.0f + dY*dY) * rn;

        X = nX; Y = nY; z = nz;
        dX += dX2 * STEP;
        dY += dY2 * STEP;

        if (nb == 0) meshXT[s*NRAY2 + ray] = X*2.0f - 1.0f;
        if (nb == 1) meshYT[s*NRAY2 + ray] = Y*2.0f - 1.0f;

        cx_ = ncx; cy_ = ncy; cz_ = ncz;
        Xn1 = mX1; Yn1 = mY1; Zn1 = mZ1;
        Xn2 = mX2; Yn2 = mY2; Zn2 = mZ2;
        ri1 = ri1n; ri2 = ri2n;
    }
}

// ---------------- kernel 2: fused resize + grid sample ----------------------
typedef _Float16 h16;
typedef _Float16 h16v4 __attribute__((ext_vector_type(4)));

__global__ __launch_bounds__(1024) void sample_kernel(
    const float* __restrict__ vol,      // 192^3
    const float* __restrict__ meshXT,   // (64, 4096)
    const float* __restrict__ meshYT,
    h16*   __restrict__ outTh,          // fp16 transposed out [c][a*192+b]
    float* __restrict__ outDirect,      // fallback fp32 out [a][b][c]
    int transposed)
{
    __shared__ h16    plane_h[PLANE];     // 73,728 B
    __shared__ float2 slice[64*64];       // 32,768 B
    __shared__ float  wTab[PHD];
    __shared__ int    iTab[PHD];

    const int tid = threadIdx.x;
    const int blk = blockIdx.x;
    const int c = (blk >> 3) + 24 * (blk & 7);   // consecutive c on same XCD

    if (tid < PHD) {
        float p = tid * (63.0f / 191.0f);
        int i0 = min((int)p, 62);
        iTab[tid] = i0;
        wTab[tid] = p - (float)i0;
    }

    {
        const float4* src = (const float4*)(vol + c * PLANE);
        h16v4* dst = (h16v4*)plane_h;
        #pragma unroll
        for (int k = 0; k < (PLANE/4)/1024; ++k) {
            float4 v = src[tid + k*1024];
            h16v4 hv = {(h16)v.x, (h16)v.y, (h16)v.z, (h16)v.w};
            dst[tid + k*1024] = hv;
        }
    }

    float ps = c * (63.0f / 191.0f);
    int s0 = min((int)ps, 62);
    float wc = ps - (float)s0, wc0 = 1.0f - wc;
    {
        const float* x0 = meshXT + s0*NRAY2;
        const float* x1 = meshXT + (s0+1)*NRAY2;
        const float* y0 = meshYT + s0*NRAY2;
        const float* y1 = meshYT + (s0+1)*NRAY2;
        #pragma unroll
        for (int k = 0; k < 4096/1024; ++k) {
            int t = tid + k*1024;
            slice[t] = make_float2(x0[t]*wc0 + x1[t]*wc,
                                   y0[t]*wc0 + y1[t]*wc);
        }
    }
    __syncthreads();

    int a = tid / PHD, b = tid % PHD;
    #pragma unroll 4
    for (int k = 0; k < PLANE/1024; ++k) {
        int i0 = iTab[a]; float wa = wTab[a];
        int j0 = iTab[b]; float wb = wTab[b];

        float2 s00 = slice[i0*64 + j0];
        float2 s01 = slice[i0*64 + j0 + 1];
        float2 s10 = slice[(i0+1)*64 + j0];
        float2 s11 = slice[(i0+1)*64 + j0 + 1];

        float wb0 = 1.0f - wb, wa0 = 1.0f - wa;
        float gx = (s00.x*wb0 + s01.x*wb)*wa0 + (s10.x*wb0 + s11.x*wb)*wa;
        float gy = (s00.y*wb0 + s01.y*wb)*wa0 + (s10.y*wb0 + s11.y*wb)*wa;

        float ix = (gx + 1.0f) * 0.5f * 191.0f;
        float iy = (gy + 1.0f) * 0.5f * 191.0f;
        float x0f = floorf(ix); float fx = ix - x0f;
        float y0f = floorf(iy); float fy = iy - y0f;

        float acc = 0.0f;
        #pragma unroll
        for (int dyy = 0; dyy < 2; ++dyy) {
            #pragma unroll
            for (int dxx = 0; dxx < 2; ++dxx) {
                float xi = x0f + (float)dxx;
                float yi = y0f + (float)dyy;
                bool inb = (xi >= 0.0f) && (xi <= 191.0f) &&
                           (yi >= 0.0f) && (yi <= 191.0f);
                int xc = min(max((int)xi, 0), PHD - 1);
                int yc = min(max((int)yi, 0), PHD - 1);
                float w = (dxx ? fx : 1.0f - fx) * (dyy ? fy : 1.0f - fy);
                float val = (float)plane_h[yc*PHD + xc];
                acc += inb ? w * val : 0.0f;
            }
        }

        if (transposed) {
            outTh[c*PLANE + tid + k*1024] = (h16)acc;   // contiguous
        } else {
            outDirect[(a*PHD + b)*PHD + c] = acc;
        }

        a += 5; b += 64;
        if (b >= PHD) { b -= PHD; a += 1; }
    }
}

// ---------------- kernel 3: (b,c) tile transpose, fp16 -> fp32 --------------
__global__ __launch_bounds__(256) void transpose_kernel(
    const h16* __restrict__ outTh, float* __restrict__ out)
{
    __shared__ h16 t[64][66];
    const int a  = blockIdx.z;
    const int b0 = blockIdx.x * 64;
    const int c0 = blockIdx.y * 64;
    const int tx = threadIdx.x & 63;
    const int ty = threadIdx.x >> 6;     // 0..3

    const h16* src = outTh + (size_t)(c0 + ty) * PLANE + a*PHD + b0 + tx;
    #pragma unroll
    for (int j = 0; j < 16; ++j)
        t[ty + 4*j][tx] = src[(size_t)(4*j) * PLANE];
    __syncthreads();

    float* dst = out + (size_t)a * PLANE + (size_t)(b0 + ty) * PHD + c0 + tx;
    #pragma unroll
    for (int j = 0; j < 16; ++j)
        dst[(size_t)(4*j) * PHD] = (float)t[tx][ty + 4*j];
}

// ---------------- launch -----------------------------------------------------
extern "C" void kernel_launch(void* const* d_in, const int* in_sizes, int n_in,
                              void* d_out, int out_size, void* d_ws, size_t ws_size,
                              hipStream_t stream)
{
    const float* Phantom = (const float*)d_in[0];   // 192^3
    const float* RI      = (const float*)d_in[1];   // (64^3, 2)
    const float* RayInit = (const float*)d_in[2];   // (4096, 5)
    float* out = (float*)d_out;

    float* meshXT = (float*)d_ws;                   // (64, 4096)   1 MB
    float* meshYT = meshXT + NRAY2 * NSAMP;         // (64, 4096)   1 MB
    h16*   outTh  = (h16*)(meshYT + NRAY2 * NSAMP); // 192^3 fp16   14.2 MB

    const size_t need = (size_t)(2 * NRAY2 * NSAMP) * sizeof(float)
                      + (size_t)PHD * PLANE * sizeof(h16);
    const int use_transpose = (ws_size >= need) ? 1 : 0;

    Mats M;
    build_mats(M);

    ray_trace_kernel<<<NRAY2/16, 256, 0, stream>>>(RI, RayInit, meshXT, meshYT, M);

    if (use_transpose) {
        sample_kernel<<<PHD, 1024, 0, stream>>>(Phantom, meshXT, meshYT,
                                                outTh, nullptr, 1);
        transpose_kernel<<<dim3(3, 3, PHD), 256, 0, stream>>>(outTh, out);
    } else {
        sample_kernel<<<PHD, 1024, 0, stream>>>(Phantom, meshXT, meshYT,
                                                nullptr, out, 0);
    }
}

// Round 8
// 148.427 us; speedup vs baseline: 1.0235x; 1.0235x over previous
//
#include <hip/hip_runtime.h>
#include <math.h>

#define NRAY2 4096
#define NSAMP 64
#define PHD 192
#define PLANE (PHD*PHD)          // 36864
constexpr float STEP = 1.0f / 63.0f;

struct Mats { float crd[16]; float drv[16]; };

// ---------------- host-side constant matrices (replicates numpy fp64 math) ---
static void mat_mul4(const double* A, const double* B, double* C) {
    for (int i = 0; i < 4; ++i)
        for (int j = 0; j < 4; ++j) {
            double s = 0.0;
            for (int k = 0; k < 4; ++k) s += A[i*4+k] * B[k*4+j];
            C[i*4+j] = s;
        }
}

static void build_mats(Mats& M) {
    const double tx = 0.1, ty = 0.05, tz = 0.02;
    const double cx = 0.5, cy = 0.5, cz = 0.5;
    auto ry = [](double t, double* m) {
        double c = cos(t), s = sin(t);
        double v[16] = {1,0,0,0, 0,c,-s,0, 0,s,c,0, 0,0,0,1};
        for (int i = 0; i < 16; ++i) m[i] = v[i];
    };
    auto rx = [](double t, double* m) {
        double c = cos(t), s = sin(t);
        double v[16] = {c,0,-s,0, 0,1,0,0, s,0,c,0, 0,0,0,1};
        for (int i = 0; i < 16; ++i) m[i] = v[i];
    };
    auto rz = [](double t, double* m) {
        double c = cos(t), s = sin(t);
        double v[16] = {c,-s,0,0, s,c,0,0, 0,0,1,0, 0,0,0,1};
        for (int i = 0; i < 16; ++i) m[i] = v[i];
    };
    double RY[16], RY_[16], RX[16], RX_[16], RZ[16], RZ_[16];
    ry(-ty, RY); ry(ty, RY_);
    rx(tx, RX);  rx(-tx, RX_);
    rz(-tz, RZ); rz(tz, RZ_);
    double S1[16] = {1,0,0,0, 0,1,0,0, 0,0,1,0, -cx,-cy,-cz,1};
    double S2[16] = {1,0,0,0, 0,1,0,0, 0,0,1,0,  cx, cy, cz,1};
    double t1[16], t2[16], t3[16], Mc[16], Md[16];
    mat_mul4(S1, RZ, t1);
    mat_mul4(t1, RY, t2);
    mat_mul4(t2, RX, t3);
    mat_mul4(t3, S2, Mc);
    mat_mul4(RX_, RY_, t1);
    mat_mul4(t1, RZ_, Md);
    for (int i = 0; i < 16; ++i) { M.crd[i] = (float)Mc[i]; M.drv[i] = (float)Md[i]; }
}

// One butterfly level applied to all 8 values (chains overlap).
template<int CTRL>
__device__ __forceinline__ void dpp_level8(float* v) {
    int t[8];
    #pragma unroll
    for (int i = 0; i < 8; ++i)
        t[i] = __builtin_amdgcn_update_dpp(0, __float_as_int(v[i]), CTRL, 0xF, 0xF, true);
    #pragma unroll
    for (int i = 0; i < 8; ++i) v[i] += __int_as_float(t[i]);
}

// 16-lane allreduce of 8 values: 4 pure-DPP row_ror levels, no LDS waits.
__device__ __forceinline__ void red8_16(float* v) {
    dpp_level8<0x121>(v);   // row_ror:1
    dpp_level8<0x122>(v);   // row_ror:2
    dpp_level8<0x124>(v);   // row_ror:4
    dpp_level8<0x128>(v);   // row_ror:8
}

// ---------------- kernel 1: ray tracing -------------------------------------
// 16 lanes per ray, 2 neighbors per lane. 64-thread blocks (1 wave each) for
// even SIMD spread: 1024 single-wave blocks over 1024 SIMDs.
__global__ __launch_bounds__(64) void ray_trace_kernel(
    const float* __restrict__ RI,       // (64^3, 2) interleaved [A, sig]
    const float* __restrict__ RayInit,  // (4096, 5)
    float* __restrict__ meshXT,         // (64, 4096)  stores 2X-1
    float* __restrict__ meshYT,         // (64, 4096)  stores 2Y-1
    Mats M)
{
    const int tid = threadIdx.x;
    const int nb  = tid & 15;                        // lane within 16-row
    const int ray = blockIdx.x * 4 + (tid >> 4);
    const bool act2 = nb < 11;                       // second neighbor active

    const int n1 = nb, n2 = nb + 16;
    const float xr1 = (float)((n1/3)%3 - 1), yr1 = (float)(n1/9 - 1), zr1 = (float)(n1%3 - 1);
    const float xr2 = (float)((n2/3)%3 - 1), yr2 = (float)(n2/9 - 1), zr2 = (float)(n2%3 - 1);

    float X  = RayInit[ray*5 + 0];
    float dX = RayInit[ray*5 + 1];
    float Y  = RayInit[ray*5 + 2];
    float dY = RayInit[ray*5 + 3];
    float z  = RayInit[ray*5 + 4];

    if (nb == 0) meshXT[ray] = X*2.0f - 1.0f;
    if (nb == 1) meshYT[ray] = Y*2.0f - 1.0f;

    auto prep = [&](float pX, float pY, float pz,
                    float& ox, float& oy, float& oz,
                    float& X1, float& Y1, float& Z1,
                    float& X2, float& Y2, float& Z2,
                    float2& r1, float2& r2) {
        float x  = pY*M.crd[1] + pX*M.crd[5] + pz*M.crd[9]  + M.crd[13];
        float y  = pY*M.crd[0] + pX*M.crd[4] + pz*M.crd[8]  + M.crd[12];
        float zz = pY*M.crd[2] + pX*M.crd[6] + pz*M.crd[10] + M.crd[14];
        float rx_ = rintf(x*64.0f), ry_ = rintf(y*64.0f), rz_ = rintf(zz*64.0f);
        X1 = __builtin_amdgcn_fmed3f(rx_ + xr1, 0.0f, 63.0f);
        Y1 = __builtin_amdgcn_fmed3f(ry_ + yr1, 0.0f, 63.0f);
        Z1 = __builtin_amdgcn_fmed3f(rz_ + zr1, 0.0f, 63.0f);
        X2 = __builtin_amdgcn_fmed3f(rx_ + xr2, 0.0f, 63.0f);
        Y2 = __builtin_amdgcn_fmed3f(ry_ + yr2, 0.0f, 63.0f);
        Z2 = __builtin_amdgcn_fmed3f(rz_ + zr2, 0.0f, 63.0f);
        int l1 = (int)(Y1*4096.0f + X1*64.0f + Z1);   // exact in fp32
        int l2 = (int)(Y2*4096.0f + X2*64.0f + Z2);
        r1 = ((const float2*)RI)[l1];
        r2 = ((const float2*)RI)[l2];
        ox = x; oy = y; oz = zz;
    };

    float cx_, cy_, cz_, Xn1, Yn1, Zn1, Xn2, Yn2, Zn2;
    float2 ri1, ri2;
    prep(X, Y, z, cx_, cy_, cz_, Xn1, Yn1, Zn1, Xn2, Yn2, Zn2, ri1, ri2);

    // v_exp_f32 computes 2^x: fold -0.5*log2(e) into the Gaussian constant.
    const float C = -0.72134752044448169f;   // -0.5 * log2(e)

    #pragma unroll 3
    for (int s = 1; s < NSAMP; ++s) {
        // one-step-ahead prefetch (uses only pre-reduction state)
        float nX = X + dX*STEP, nY = Y + dY*STEP, nz = z + STEP;
        float ncx, ncy, ncz, mX1, mY1, mZ1, mX2, mY2, mZ2;
        float2 ri1n, ri2n;
        prep(nX, nY, nz, ncx, ncy, ncz, mX1, mY1, mZ1, mX2, mY2, mZ2, ri1n, ri2n);

        // neighbor 1 contribution
        float dx1 = Xn1*(1.0f/63.0f) - cx_;
        float dy1 = Yn1*(1.0f/63.0f) - cy_;
        float dz1 = Zn1*(1.0f/63.0f) - cz_;
        float is1 = __builtin_amdgcn_rcpf(ri1.y * ri1.y);
        float d21 = dx1*dx1 + dy1*dy1 + dz1*dz1;
        float e1  = __builtin_amdgcn_exp2f(d21 * is1 * C) + 2e-7f;
        float g1x = dx1*is1, g1y = dy1*is1, g1z = dz1*is1;
        float nu1 = e1 * ri1.x;

        // neighbor 2 contribution (zeroed when inactive)
        float dx2 = Xn2*(1.0f/63.0f) - cx_;
        float dy2 = Yn2*(1.0f/63.0f) - cy_;
        float dz2 = Zn2*(1.0f/63.0f) - cz_;
        float is2 = __builtin_amdgcn_rcpf(ri2.y * ri2.y);
        float d22 = dx2*dx2 + dy2*dy2 + dz2*dz2;
        float e2  = __builtin_amdgcn_exp2f(d22 * is2 * C) + 2e-7f;
        if (!act2) e2 = 0.0f;
        float g2x = dx2*is2, g2y = dy2*is2, g2z = dz2*is2;
        float nu2 = e2 * ri2.x;

        float v[8] = { e1 + e2,
                       nu1 + nu2,
                       nu1*g1x + nu2*g2x,
                       nu1*g1y + nu2*g2y,
                       nu1*g1z + nu2*g2z,
                       e1*g1x + e2*g2x,
                       e1*g1y + e2*g2y,
                       e1*g1z + e2*g2z };
        red8_16(v);
        float ni  = v[0], nuA = v[1];
        float sx  = v[2], sy  = v[3], sz  = v[4];
        float sdx = v[5], sdy = v[6], sdz = v[7];

        float r   = __builtin_amdgcn_rcpf(ni);
        float rn  = ni * __builtin_amdgcn_rcpf(nuA);   // 1/n = norm/nu_s
        float in2 = r * r;
        float gx_ = (ni*sx - nuA*sdx) * in2;
        float gy_ = (ni*sy - nuA*sdy) * in2;
        float gz_ = (ni*sz - nuA*sdz) * in2;

        float dndx = gy_*M.drv[1] + gx_*M.drv[5] + gz_*M.drv[9]  + M.drv[13];
        float dndy = gy_*M.drv[0] + gx_*M.drv[4] + gz_*M.drv[8]  + M.drv[12];
        float dndz = gy_*M.drv[2] + gx_*M.drv[6] + gz_*M.drv[10] + M.drv[14];

        float dX2 = (dndx - dndz*dX) * (1.0f + dX*dX) * rn;
        float dY2 = (dndy - dndz*dY) * (1.0f + dY*dY) * rn;

        X = nX; Y = nY; z = nz;
        dX += dX2 * STEP;
        dY += dY2 * STEP;

        if (nb == 0) meshXT[s*NRAY2 + ray] = X*2.0f - 1.0f;
        if (nb == 1) meshYT[s*NRAY2 + ray] = Y*2.0f - 1.0f;

        cx_ = ncx; cy_ = ncy; cz_ = ncz;
        Xn1 = mX1; Yn1 = mY1; Zn1 = mZ1;
        Xn2 = mX2; Yn2 = mY2; Zn2 = mZ2;
        ri1 = ri1n; ri2 = ri2n;
    }
}

// ---------------- kernel 2: fused resize + grid sample ----------------------
// Pack-of-4 version: each thread produces 4 consecutive transposed outputs
// (same output row a; 4 consecutive b). Since 3*(63/191) < 1, the pack spans
// at most 2 mesh cells in j -> 6 ds_read_b64 slice reads per pack (3 cols x
// 2 rows, a-lerp hoisted) instead of 16. One h16x4 store per pack.
typedef _Float16 h16;
typedef _Float16 h16v4 __attribute__((ext_vector_type(4)));

__global__ __launch_bounds__(1024) void sample_kernel(
    const float* __restrict__ vol,      // 192^3
    const float* __restrict__ meshXT,   // (64, 4096)
    const float* __restrict__ meshYT,
    h16*   __restrict__ outTh,          // fp16 transposed out [c][a*192+b]
    float* __restrict__ outDirect,      // fallback fp32 out [a][b][c]
    int transposed)
{
    __shared__ h16    plane_h[PLANE];     // 73,728 B
    __shared__ float2 slice[64*64];       // 32,768 B

    const int tid = threadIdx.x;
    const int blk = blockIdx.x;
    const int c = (blk >> 3) + 24 * (blk & 7);   // consecutive c on same XCD

    const float D = 63.0f / 191.0f;

    // stage phantom plane c -> fp16 LDS (coalesced float4 loads)
    {
        const float4* src = (const float4*)(vol + c * PLANE);
        h16v4* dst = (h16v4*)plane_h;
        #pragma unroll
        for (int k = 0; k < (PLANE/4)/1024; ++k) {
            float4 v = src[tid + k*1024];
            h16v4 hv = {(h16)v.x, (h16)v.y, (h16)v.z, (h16)v.w};
            dst[tid + k*1024] = hv;
        }
    }

    // s-interpolation (block-uniform) + slice build (coalesced)
    float ps = c * D;
    int s0 = min((int)ps, 62);
    float wcs = ps - (float)s0, wc0 = 1.0f - wcs;
    {
        const float* x0 = meshXT + s0*NRAY2;
        const float* x1 = meshXT + (s0+1)*NRAY2;
        const float* y0 = meshYT + s0*NRAY2;
        const float* y1 = meshYT + (s0+1)*NRAY2;
        #pragma unroll
        for (int k = 0; k < 4096/1024; ++k) {
            int t = tid + k*1024;
            slice[t] = make_float2(x0[t]*wc0 + x1[t]*wcs,
                                   y0[t]*wc0 + y1[t]*wcs);
        }
    }
    __syncthreads();

    #pragma unroll 1
    for (int k = 0; k < PLANE/4096; ++k) {        // 9 iterations
        const int w0 = (tid + k*1024) * 4;        // linear within plane
        const int a  = w0 / PHD;                  // pack stays in one row
        const int b0 = w0 - a*PHD;

        float pa = (float)a * D;
        int   i0 = min((int)pa, 62);
        float wa = pa - (float)i0;

        float pb0 = (float)b0 * D;
        int  jmin = min((int)pb0, 62);
        int  j2   = min(jmin + 2, 63);

        float2 r0c0 = slice[i0*64 + jmin];
        float2 r0c1 = slice[i0*64 + jmin + 1];
        float2 r0c2 = slice[i0*64 + j2];
        float2 r1c0 = slice[(i0+1)*64 + jmin];
        float2 r1c1 = slice[(i0+1)*64 + jmin + 1];
        float2 r1c2 = slice[(i0+1)*64 + j2];

        // hoist the a-lerp (wa uniform across the pack)
        float c0x = r0c0.x + wa*(r1c0.x - r0c0.x);
        float c0y = r0c0.y + wa*(r1c0.y - r0c0.y);
        float c1x = r0c1.x + wa*(r1c1.x - r0c1.x);
        float c1y = r0c1.y + wa*(r1c1.y - r0c1.y);
        float c2x = r0c2.x + wa*(r1c2.x - r0c2.x);
        float c2y = r0c2.y + wa*(r1c2.y - r0c2.y);

        h16v4 res;
        #pragma unroll
        for (int m = 0; m < 4; ++m) {
            float pb = (float)(b0 + m) * D;
            int   j0 = min((int)pb, 62);
            float wb = pb - (float)j0;
            bool  hi = (j0 != jmin);

            float sax = hi ? c1x : c0x, say = hi ? c1y : c0y;
            float sbx = hi ? c2x : c1x, sby = hi ? c2y : c1y;
            float gx = sax + wb*(sbx - sax);
            float gy = say + wb*(sby - say);

            float ix = (gx + 1.0f) * 0.5f * 191.0f;
            float iy = (gy + 1.0f) * 0.5f * 191.0f;
            float x0f = floorf(ix); float fx = ix - x0f;
            float y0f = floorf(iy); float fy = iy - y0f;

            float acc = 0.0f;
            #pragma unroll
            for (int dyy = 0; dyy < 2; ++dyy) {
                #pragma unroll
                for (int dxx = 0; dxx < 2; ++dxx) {
                    float xi = x0f + (float)dxx;
                    float yi = y0f + (float)dyy;
                    bool inb = (xi >= 0.0f) && (xi <= 191.0f) &&
                               (yi >= 0.0f) && (yi <= 191.0f);
                    int xc = min(max((int)xi, 0), PHD - 1);
                    int yc = min(max((int)yi, 0), PHD - 1);
                    float w = (dxx ? fx : 1.0f - fx) * (dyy ? fy : 1.0f - fy);
                    float val = (float)plane_h[yc*PHD + xc];
                    acc += inb ? w * val : 0.0f;
                }
            }
            res[m] = (h16)acc;
        }

        if (transposed) {
            *(h16v4*)(outTh + (size_t)c*PLANE + w0) = res;   // 8 B contiguous
        } else {
            #pragma unroll
            for (int m = 0; m < 4; ++m)
                outDirect[(size_t)(a*PHD + b0 + m)*PHD + c] = (float)res[m];
        }
    }
}

// ---------------- kernel 3: (b,c) tile transpose, fp16 -> fp32 --------------
__global__ __launch_bounds__(256) void transpose_kernel(
    const h16* __restrict__ outTh, float* __restrict__ out)
{
    __shared__ h16 t[64][66];
    const int a  = blockIdx.z;
    const int b0 = blockIdx.x * 64;
    const int c0 = blockIdx.y * 64;
    const int tx = threadIdx.x & 63;
    const int ty = threadIdx.x >> 6;     // 0..3

    const h16* src = outTh + (size_t)(c0 + ty) * PLANE + a*PHD + b0 + tx;
    #pragma unroll
    for (int j = 0; j < 16; ++j)
        t[ty + 4*j][tx] = src[(size_t)(4*j) * PLANE];
    __syncthreads();

    float* dst = out + (size_t)a * PLANE + (size_t)(b0 + ty) * PHD + c0 + tx;
    #pragma unroll
    for (int j = 0; j < 16; ++j)
        dst[(size_t)(4*j) * PHD] = (float)t[tx][ty + 4*j];
}

// ---------------- launch -----------------------------------------------------
extern "C" void kernel_launch(void* const* d_in, const int* in_sizes, int n_in,
                              void* d_out, int out_size, void* d_ws, size_t ws_size,
                              hipStream_t stream)
{
    const float* Phantom = (const float*)d_in[0];   // 192^3
    const float* RI      = (const float*)d_in[1];   // (64^3, 2)
    const float* RayInit = (const float*)d_in[2];   // (4096, 5)
    float* out = (float*)d_out;

    float* meshXT = (float*)d_ws;                   // (64, 4096)   1 MB
    float* meshYT = meshXT + NRAY2 * NSAMP;         // (64, 4096)   1 MB
    h16*   outTh  = (h16*)(meshYT + NRAY2 * NSAMP); // 192^3 fp16   14.2 MB

    const size_t need = (size_t)(2 * NRAY2 * NSAMP) * sizeof(float)
                      + (size_t)PHD * PLANE * sizeof(h16);
    const int use_transpose = (ws_size >= need) ? 1 : 0;

    Mats M;
    build_mats(M);

    ray_trace_kernel<<<NRAY2/4, 64, 0, stream>>>(RI, RayInit, meshXT, meshYT, M);

    if (use_transpose) {
        sample_kernel<<<PHD, 1024, 0, stream>>>(Phantom, meshXT, meshYT,
                                                outTh, nullptr, 1);
        transpose_kernel<<<dim3(3, 3, PHD), 256, 0, stream>>>(outTh, out);
    } else {
        sample_kernel<<<PHD, 1024, 0, stream>>>(Phantom, meshXT, meshYT,
                                                nullptr, out, 0);
    }
}

// Round 9
// 140.987 us; speedup vs baseline: 1.0775x; 1.0528x over previous
//
#include <hip/hip_runtime.h>
#include <math.h>

#define NRAY2 4096
#define NSAMP 64
#define PHD 192
#define PLANE (PHD*PHD)          // 36864
constexpr float STEP = 1.0f / 63.0f;

struct Mats { float crd[16]; float drv[16]; };

// ---------------- host-side constant matrices (replicates numpy fp64 math) ---
static void mat_mul4(const double* A, const double* B, double* C) {
    for (int i = 0; i < 4; ++i)
        for (int j = 0; j < 4; ++j) {
            double s = 0.0;
            for (int k = 0; k < 4; ++k) s += A[i*4+k] * B[k*4+j];
            C[i*4+j] = s;
        }
}

static void build_mats(Mats& M) {
    const double tx = 0.1, ty = 0.05, tz = 0.02;
    const double cx = 0.5, cy = 0.5, cz = 0.5;
    auto ry = [](double t, double* m) {
        double c = cos(t), s = sin(t);
        double v[16] = {1,0,0,0, 0,c,-s,0, 0,s,c,0, 0,0,0,1};
        for (int i = 0; i < 16; ++i) m[i] = v[i];
    };
    auto rx = [](double t, double* m) {
        double c = cos(t), s = sin(t);
        double v[16] = {c,0,-s,0, 0,1,0,0, s,0,c,0, 0,0,0,1};
        for (int i = 0; i < 16; ++i) m[i] = v[i];
    };
    auto rz = [](double t, double* m) {
        double c = cos(t), s = sin(t);
        double v[16] = {c,-s,0,0, s,c,0,0, 0,0,1,0, 0,0,0,1};
        for (int i = 0; i < 16; ++i) m[i] = v[i];
    };
    double RY[16], RY_[16], RX[16], RX_[16], RZ[16], RZ_[16];
    ry(-ty, RY); ry(ty, RY_);
    rx(tx, RX);  rx(-tx, RX_);
    rz(-tz, RZ); rz(tz, RZ_);
    double S1[16] = {1,0,0,0, 0,1,0,0, 0,0,1,0, -cx,-cy,-cz,1};
    double S2[16] = {1,0,0,0, 0,1,0,0, 0,0,1,0,  cx, cy, cz,1};
    double t1[16], t2[16], t3[16], Mc[16], Md[16];
    mat_mul4(S1, RZ, t1);
    mat_mul4(t1, RY, t2);
    mat_mul4(t2, RX, t3);
    mat_mul4(t3, S2, Mc);
    mat_mul4(RX_, RY_, t1);
    mat_mul4(t1, RZ_, Md);
    for (int i = 0; i < 16; ++i) { M.crd[i] = (float)Mc[i]; M.drv[i] = (float)Md[i]; }
}

// One butterfly level applied to all 8 values (chains overlap).
template<int CTRL>
__device__ __forceinline__ void dpp_level8(float* v) {
    int t[8];
    #pragma unroll
    for (int i = 0; i < 8; ++i)
        t[i] = __builtin_amdgcn_update_dpp(0, __float_as_int(v[i]), CTRL, 0xF, 0xF, true);
    #pragma unroll
    for (int i = 0; i < 8; ++i) v[i] += __int_as_float(t[i]);
}

// 16-lane allreduce of 8 values: 4 pure-DPP row_ror levels, no LDS waits.
__device__ __forceinline__ void red8_16(float* v) {
    dpp_level8<0x121>(v);   // row_ror:1
    dpp_level8<0x122>(v);   // row_ror:2
    dpp_level8<0x124>(v);   // row_ror:4
    dpp_level8<0x128>(v);   // row_ror:8
}

// ---------------- kernel 1: ray tracing -------------------------------------
// 16 lanes per ray, 2 neighbors per lane, 1 wave per block (4 rays).
// KEY CHANGE (R9): no global stores inside the step loop. Per-step mesh
// values go to a 2 KB LDS buffer (ds_write -> lgkm, NOT vmcnt); the loop's
// VMEM queue holds only the 2 prefetch loads, so the compiler's conservative
// vmcnt(0) at the loop-carried ri use no longer drains store-acks. Mesh is
// written once at the end with coalesced float4 stores.
__global__ __launch_bounds__(64) void ray_trace_kernel(
    const float* __restrict__ RI,       // (64^3, 2) interleaved [A, sig]
    const float* __restrict__ RayInit,  // (4096, 5)
    float* __restrict__ meshXT,         // (64, 4096)  stores 2X-1
    float* __restrict__ meshYT,         // (64, 4096)  stores 2Y-1
    Mats M)
{
    __shared__ float lX[NSAMP][4];      // [s][ray_local]  1 KB
    __shared__ float lY[NSAMP][4];      // 1 KB

    const int tid = threadIdx.x;
    const int nb  = tid & 15;                        // lane within 16-row
    const int rl  = tid >> 4;                        // ray local 0..3
    const int ray = blockIdx.x * 4 + rl;
    const bool act2 = nb < 11;                       // second neighbor active

    const int n1 = nb, n2 = nb + 16;
    const float xr1 = (float)((n1/3)%3 - 1), yr1 = (float)(n1/9 - 1), zr1 = (float)(n1%3 - 1);
    const float xr2 = (float)((n2/3)%3 - 1), yr2 = (float)(n2/9 - 1), zr2 = (float)(n2%3 - 1);

    float X  = RayInit[ray*5 + 0];
    float dX = RayInit[ray*5 + 1];
    float Y  = RayInit[ray*5 + 2];
    float dY = RayInit[ray*5 + 3];
    float z  = RayInit[ray*5 + 4];

    if (nb == 0) { lX[0][rl] = X*2.0f - 1.0f; lY[0][rl] = Y*2.0f - 1.0f; }

    auto prep = [&](float pX, float pY, float pz,
                    float& ox, float& oy, float& oz,
                    float& X1, float& Y1, float& Z1,
                    float& X2, float& Y2, float& Z2,
                    float2& r1, float2& r2) {
        float x  = pY*M.crd[1] + pX*M.crd[5] + pz*M.crd[9]  + M.crd[13];
        float y  = pY*M.crd[0] + pX*M.crd[4] + pz*M.crd[8]  + M.crd[12];
        float zz = pY*M.crd[2] + pX*M.crd[6] + pz*M.crd[10] + M.crd[14];
        float rx_ = rintf(x*64.0f), ry_ = rintf(y*64.0f), rz_ = rintf(zz*64.0f);
        X1 = __builtin_amdgcn_fmed3f(rx_ + xr1, 0.0f, 63.0f);
        Y1 = __builtin_amdgcn_fmed3f(ry_ + yr1, 0.0f, 63.0f);
        Z1 = __builtin_amdgcn_fmed3f(rz_ + zr1, 0.0f, 63.0f);
        X2 = __builtin_amdgcn_fmed3f(rx_ + xr2, 0.0f, 63.0f);
        Y2 = __builtin_amdgcn_fmed3f(ry_ + yr2, 0.0f, 63.0f);
        Z2 = __builtin_amdgcn_fmed3f(rz_ + zr2, 0.0f, 63.0f);
        int l1 = (int)(Y1*4096.0f + X1*64.0f + Z1);   // exact in fp32
        int l2 = (int)(Y2*4096.0f + X2*64.0f + Z2);
        r1 = ((const float2*)RI)[l1];
        r2 = ((const float2*)RI)[l2];
        ox = x; oy = y; oz = zz;
    };

    float cx_, cy_, cz_, Xn1, Yn1, Zn1, Xn2, Yn2, Zn2;
    float2 ri1, ri2;
    prep(X, Y, z, cx_, cy_, cz_, Xn1, Yn1, Zn1, Xn2, Yn2, Zn2, ri1, ri2);

    // v_exp_f32 computes 2^x: fold -0.5*log2(e) into the Gaussian constant.
    const float C = -0.72134752044448169f;   // -0.5 * log2(e)

    for (int s = 1; s < NSAMP; ++s) {
        // one-step-ahead prefetch (uses only pre-reduction state)
        float nX = X + dX*STEP, nY = Y + dY*STEP, nz = z + STEP;
        float ncx, ncy, ncz, mX1, mY1, mZ1, mX2, mY2, mZ2;
        float2 ri1n, ri2n;
        prep(nX, nY, nz, ncx, ncy, ncz, mX1, mY1, mZ1, mX2, mY2, mZ2, ri1n, ri2n);

        // neighbor 1 contribution
        float dx1 = Xn1*(1.0f/63.0f) - cx_;
        float dy1 = Yn1*(1.0f/63.0f) - cy_;
        float dz1 = Zn1*(1.0f/63.0f) - cz_;
        float is1 = __builtin_amdgcn_rcpf(ri1.y * ri1.y);
        float d21 = dx1*dx1 + dy1*dy1 + dz1*dz1;
        float e1  = __builtin_amdgcn_exp2f(d21 * is1 * C) + 2e-7f;
        float g1x = dx1*is1, g1y = dy1*is1, g1z = dz1*is1;
        float nu1 = e1 * ri1.x;

        // neighbor 2 contribution (zeroed when inactive)
        float dx2 = Xn2*(1.0f/63.0f) - cx_;
        float dy2 = Yn2*(1.0f/63.0f) - cy_;
        float dz2 = Zn2*(1.0f/63.0f) - cz_;
        float is2 = __builtin_amdgcn_rcpf(ri2.y * ri2.y);
        float d22 = dx2*dx2 + dy2*dy2 + dz2*dz2;
        float e2  = __builtin_amdgcn_exp2f(d22 * is2 * C) + 2e-7f;
        if (!act2) e2 = 0.0f;
        float g2x = dx2*is2, g2y = dy2*is2, g2z = dz2*is2;
        float nu2 = e2 * ri2.x;

        float v[8] = { e1 + e2,
                       nu1 + nu2,
                       nu1*g1x + nu2*g2x,
                       nu1*g1y + nu2*g2y,
                       nu1*g1z + nu2*g2z,
                       e1*g1x + e2*g2x,
                       e1*g1y + e2*g2y,
                       e1*g1z + e2*g2z };
        red8_16(v);
        float ni  = v[0], nuA = v[1];
        float sx  = v[2], sy  = v[3], sz  = v[4];
        float sdx = v[5], sdy = v[6], sdz = v[7];

        float r   = __builtin_amdgcn_rcpf(ni);
        float rn  = ni * __builtin_amdgcn_rcpf(nuA);   // 1/n = norm/nu_s
        float in2 = r * r;
        float gx_ = (ni*sx - nuA*sdx) * in2;
        float gy_ = (ni*sy - nuA*sdy) * in2;
        float gz_ = (ni*sz - nuA*sdz) * in2;

        float dndx = gy_*M.drv[1] + gx_*M.drv[5] + gz_*M.drv[9]  + M.drv[13];
        float dndy = gy_*M.drv[0] + gx_*M.drv[4] + gz_*M.drv[8]  + M.drv[12];
        float dndz = gy_*M.drv[2] + gx_*M.drv[6] + gz_*M.drv[10] + M.drv[14];

        float dX2 = (dndx - dndz*dX) * (1.0f + dX*dX) * rn;
        float dY2 = (dndy - dndz*dY) * (1.0f + dY*dY) * rn;

        X = nX; Y = nY; z = nz;
        dX += dX2 * STEP;
        dY += dY2 * STEP;

        // LDS buffer instead of global store: keeps vmcnt queue loads-only
        if (nb == 0) { lX[s][rl] = X*2.0f - 1.0f; lY[s][rl] = Y*2.0f - 1.0f; }

        cx_ = ncx; cy_ = ncy; cz_ = ncz;
        Xn1 = mX1; Yn1 = mY1; Zn1 = mZ1;
        Xn2 = mX2; Yn2 = mY2; Zn2 = mZ2;
        ri1 = ri1n; ri2 = ri2n;
    }

    __syncthreads();   // single wave: cheap; orders ds_writes before reads

    // bulk writeout: lane s stores this block's 4 rays as one float4 per array
    {
        const int s = tid;                     // 0..63
        const int ray0 = blockIdx.x * 4;
        float4 vx = *(const float4*)&lX[s][0];
        float4 vy = *(const float4*)&lY[s][0];
        *(float4*)&meshXT[s*NRAY2 + ray0] = vx;
        *(float4*)&meshYT[s*NRAY2 + ray0] = vy;
    }
}

// ---------------- kernel 2: fused resize + grid sample ----------------------
// Pack-of-4 version (unchanged from R8).
typedef _Float16 h16;
typedef _Float16 h16v4 __attribute__((ext_vector_type(4)));

__global__ __launch_bounds__(1024) void sample_kernel(
    const float* __restrict__ vol,      // 192^3
    const float* __restrict__ meshXT,   // (64, 4096)
    const float* __restrict__ meshYT,
    h16*   __restrict__ outTh,          // fp16 transposed out [c][a*192+b]
    float* __restrict__ outDirect,      // fallback fp32 out [a][b][c]
    int transposed)
{
    __shared__ h16    plane_h[PLANE];     // 73,728 B
    __shared__ float2 slice[64*64];       // 32,768 B

    const int tid = threadIdx.x;
    const int blk = blockIdx.x;
    const int c = (blk >> 3) + 24 * (blk & 7);   // consecutive c on same XCD

    const float D = 63.0f / 191.0f;

    {
        const float4* src = (const float4*)(vol + c * PLANE);
        h16v4* dst = (h16v4*)plane_h;
        #pragma unroll
        for (int k = 0; k < (PLANE/4)/1024; ++k) {
            float4 v = src[tid + k*1024];
            h16v4 hv = {(h16)v.x, (h16)v.y, (h16)v.z, (h16)v.w};
            dst[tid + k*1024] = hv;
        }
    }

    float ps = c * D;
    int s0 = min((int)ps, 62);
    float wcs = ps - (float)s0, wc0 = 1.0f - wcs;
    {
        const float* x0 = meshXT + s0*NRAY2;
        const float* x1 = meshXT + (s0+1)*NRAY2;
        const float* y0 = meshYT + s0*NRAY2;
        const float* y1 = meshYT + (s0+1)*NRAY2;
        #pragma unroll
        for (int k = 0; k < 4096/1024; ++k) {
            int t = tid + k*1024;
            slice[t] = make_float2(x0[t]*wc0 + x1[t]*wcs,
                                   y0[t]*wc0 + y1[t]*wcs);
        }
    }
    __syncthreads();

    #pragma unroll 1
    for (int k = 0; k < PLANE/4096; ++k) {        // 9 iterations
        const int w0 = (tid + k*1024) * 4;        // linear within plane
        const int a  = w0 / PHD;                  // pack stays in one row
        const int b0 = w0 - a*PHD;

        float pa = (float)a * D;
        int   i0 = min((int)pa, 62);
        float wa = pa - (float)i0;

        float pb0 = (float)b0 * D;
        int  jmin = min((int)pb0, 62);
        int  j2   = min(jmin + 2, 63);

        float2 r0c0 = slice[i0*64 + jmin];
        float2 r0c1 = slice[i0*64 + jmin + 1];
        float2 r0c2 = slice[i0*64 + j2];
        float2 r1c0 = slice[(i0+1)*64 + jmin];
        float2 r1c1 = slice[(i0+1)*64 + jmin + 1];
        float2 r1c2 = slice[(i0+1)*64 + j2];

        float c0x = r0c0.x + wa*(r1c0.x - r0c0.x);
        float c0y = r0c0.y + wa*(r1c0.y - r0c0.y);
        float c1x = r0c1.x + wa*(r1c1.x - r0c1.x);
        float c1y = r0c1.y + wa*(r1c1.y - r0c1.y);
        float c2x = r0c2.x + wa*(r1c2.x - r0c2.x);
        float c2y = r0c2.y + wa*(r1c2.y - r0c2.y);

        h16v4 res;
        #pragma unroll
        for (int m = 0; m < 4; ++m) {
            float pb = (float)(b0 + m) * D;
            int   j0 = min((int)pb, 62);
            float wb = pb - (float)j0;
            bool  hi = (j0 != jmin);

            float sax = hi ? c1x : c0x, say = hi ? c1y : c0y;
            float sbx = hi ? c2x : c1x, sby = hi ? c2y : c1y;
            float gx = sax + wb*(sbx - sax);
            float gy = say + wb*(sby - say);

            float ix = (gx + 1.0f) * 0.5f * 191.0f;
            float iy = (gy + 1.0f) * 0.5f * 191.0f;
            float x0f = floorf(ix); float fx = ix - x0f;
            float y0f = floorf(iy); float fy = iy - y0f;

            float acc = 0.0f;
            #pragma unroll
            for (int dyy = 0; dyy < 2; ++dyy) {
                #pragma unroll
                for (int dxx = 0; dxx < 2; ++dxx) {
                    float xi = x0f + (float)dxx;
                    float yi = y0f + (float)dyy;
                    bool inb = (xi >= 0.0f) && (xi <= 191.0f) &&
                               (yi >= 0.0f) && (yi <= 191.0f);
                    int xc = min(max((int)xi, 0), PHD - 1);
                    int yc = min(max((int)yi, 0), PHD - 1);
                    float w = (dxx ? fx : 1.0f - fx) * (dyy ? fy : 1.0f - fy);
                    float val = (float)plane_h[yc*PHD + xc];
                    acc += inb ? w * val : 0.0f;
                }
            }
            res[m] = (h16)acc;
        }

        if (transposed) {
            *(h16v4*)(outTh + (size_t)c*PLANE + w0) = res;   // 8 B contiguous
        } else {
            #pragma unroll
            for (int m = 0; m < 4; ++m)
                outDirect[(size_t)(a*PHD + b0 + m)*PHD + c] = (float)res[m];
        }
    }
}

// ---------------- kernel 3: (b,c) tile transpose, fp16 -> fp32 --------------
__global__ __launch_bounds__(256) void transpose_kernel(
    const h16* __restrict__ outTh, float* __restrict__ out)
{
    __shared__ h16 t[64][66];
    const int a  = blockIdx.z;
    const int b0 = blockIdx.x * 64;
    const int c0 = blockIdx.y * 64;
    const int tx = threadIdx.x & 63;
    const int ty = threadIdx.x >> 6;     // 0..3

    const h16* src = outTh + (size_t)(c0 + ty) * PLANE + a*PHD + b0 + tx;
    #pragma unroll
    for (int j = 0; j < 16; ++j)
        t[ty + 4*j][tx] = src[(size_t)(4*j) * PLANE];
    __syncthreads();

    float* dst = out + (size_t)a * PLANE + (size_t)(b0 + ty) * PHD + c0 + tx;
    #pragma unroll
    for (int j = 0; j < 16; ++j)
        dst[(size_t)(4*j) * PHD] = (float)t[tx][ty + 4*j];
}

// ---------------- launch -----------------------------------------------------
extern "C" void kernel_launch(void* const* d_in, const int* in_sizes, int n_in,
                              void* d_out, int out_size, void* d_ws, size_t ws_size,
                              hipStream_t stream)
{
    const float* Phantom = (const float*)d_in[0];   // 192^3
    const float* RI      = (const float*)d_in[1];   // (64^3, 2)
    const float* RayInit = (const float*)d_in[2];   // (4096, 5)
    float* out = (float*)d_out;

    float* meshXT = (float*)d_ws;                   // (64, 4096)   1 MB
    float* meshYT = meshXT + NRAY2 * NSAMP;         // (64, 4096)   1 MB
    h16*   outTh  = (h16*)(meshYT + NRAY2 * NSAMP); // 192^3 fp16   14.2 MB

    const size_t need = (size_t)(2 * NRAY2 * NSAMP) * sizeof(float)
                      + (size_t)PHD * PLANE * sizeof(h16);
    const int use_transpose = (ws_size >= need) ? 1 : 0;

    Mats M;
    build_mats(M);

    ray_trace_kernel<<<NRAY2/4, 64, 0, stream>>>(RI, RayInit, meshXT, meshYT, M);

    if (use_transpose) {
        sample_kernel<<<PHD, 1024, 0, stream>>>(Phantom, meshXT, meshYT,
                                                outTh, nullptr, 1);
        transpose_kernel<<<dim3(3, 3, PHD), 256, 0, stream>>>(outTh, out);
    } else {
        sample_kernel<<<PHD, 1024, 0, stream>>>(Phantom, meshXT, meshYT,
                                                nullptr, out, 0);
    }
}

// Round 10
// 139.232 us; speedup vs baseline: 1.0911x; 1.0126x over previous
//
#include <hip/hip_runtime.h>
#include <math.h>

#define NRAY2 4096
#define NSAMP 64
#define PHD 192
#define PLANE (PHD*PHD)          // 36864
constexpr float STEP = 1.0f / 63.0f;

struct Mats { float crd[16]; float drv[16]; };

// ---------------- host-side constant matrices (replicates numpy fp64 math) ---
static void mat_mul4(const double* A, const double* B, double* C) {
    for (int i = 0; i < 4; ++i)
        for (int j = 0; j < 4; ++j) {
            double s = 0.0;
            for (int k = 0; k < 4; ++k) s += A[i*4+k] * B[k*4+j];
            C[i*4+j] = s;
        }
}

static void build_mats(Mats& M) {
    const double tx = 0.1, ty = 0.05, tz = 0.02;
    const double cx = 0.5, cy = 0.5, cz = 0.5;
    auto ry = [](double t, double* m) {
        double c = cos(t), s = sin(t);
        double v[16] = {1,0,0,0, 0,c,-s,0, 0,s,c,0, 0,0,0,1};
        for (int i = 0; i < 16; ++i) m[i] = v[i];
    };
    auto rx = [](double t, double* m) {
        double c = cos(t), s = sin(t);
        double v[16] = {c,0,-s,0, 0,1,0,0, s,0,c,0, 0,0,0,1};
        for (int i = 0; i < 16; ++i) m[i] = v[i];
    };
    auto rz = [](double t, double* m) {
        double c = cos(t), s = sin(t);
        double v[16] = {c,-s,0,0, s,c,0,0, 0,0,1,0, 0,0,0,1};
        for (int i = 0; i < 16; ++i) m[i] = v[i];
    };
    double RY[16], RY_[16], RX[16], RX_[16], RZ[16], RZ_[16];
    ry(-ty, RY); ry(ty, RY_);
    rx(tx, RX);  rx(-tx, RX_);
    rz(-tz, RZ); rz(tz, RZ_);
    double S1[16] = {1,0,0,0, 0,1,0,0, 0,0,1,0, -cx,-cy,-cz,1};
    double S2[16] = {1,0,0,0, 0,1,0,0, 0,0,1,0,  cx, cy, cz,1};
    double t1[16], t2[16], t3[16], Mc[16], Md[16];
    mat_mul4(S1, RZ, t1);
    mat_mul4(t1, RY, t2);
    mat_mul4(t2, RX, t3);
    mat_mul4(t3, S2, Mc);
    mat_mul4(RX_, RY_, t1);
    mat_mul4(t1, RZ_, Md);
    for (int i = 0; i < 16; ++i) { M.crd[i] = (float)Mc[i]; M.drv[i] = (float)Md[i]; }
}

// One butterfly level applied to all 8 values (chains overlap).
template<int CTRL>
__device__ __forceinline__ void dpp_level8(float* v) {
    int t[8];
    #pragma unroll
    for (int i = 0; i < 8; ++i)
        t[i] = __builtin_amdgcn_update_dpp(0, __float_as_int(v[i]), CTRL, 0xF, 0xF, true);
    #pragma unroll
    for (int i = 0; i < 8; ++i) v[i] += __int_as_float(t[i]);
}

// 16-lane allreduce of 8 values: 4 pure-DPP row_ror levels, no LDS waits.
__device__ __forceinline__ void red8_16(float* v) {
    dpp_level8<0x121>(v);   // row_ror:1
    dpp_level8<0x122>(v);   // row_ror:2
    dpp_level8<0x124>(v);   // row_ror:4
    dpp_level8<0x128>(v);   // row_ror:8
}

// ---------------- kernel 1: ray tracing -------------------------------------
// 16 lanes per ray, 2 neighbors per lane, 1 wave per block (4 rays).
// R9: no global stores in the loop (LDS buffer, bulk writeout) -> vmcnt queue
// is loads-only. R10: NOW unroll pays — with a loads-only queue, unrolled
// iterations put prefetch-issue and prior-iteration use in one basic block
// where the compiler emits precise vmcnt(N) instead of the backedge's
// conservative vmcnt(0). 63 = 7 x 9 -> unroll 7 makes 6/7 pairs intra-block.
__global__ __launch_bounds__(64) void ray_trace_kernel(
    const float* __restrict__ RI,       // (64^3, 2) interleaved [A, sig]
    const float* __restrict__ RayInit,  // (4096, 5)
    float* __restrict__ meshXT,         // (64, 4096)  stores 2X-1
    float* __restrict__ meshYT,         // (64, 4096)  stores 2Y-1
    Mats M)
{
    __shared__ float lX[NSAMP][4];      // [s][ray_local]  1 KB
    __shared__ float lY[NSAMP][4];      // 1 KB

    const int tid = threadIdx.x;
    const int nb  = tid & 15;                        // lane within 16-row
    const int rl  = tid >> 4;                        // ray local 0..3
    const int ray = blockIdx.x * 4 + rl;
    const bool act2 = nb < 11;                       // second neighbor active

    const int n1 = nb, n2 = nb + 16;
    const float xr1 = (float)((n1/3)%3 - 1), yr1 = (float)(n1/9 - 1), zr1 = (float)(n1%3 - 1);
    const float xr2 = (float)((n2/3)%3 - 1), yr2 = (float)(n2/9 - 1), zr2 = (float)(n2%3 - 1);

    float X  = RayInit[ray*5 + 0];
    float dX = RayInit[ray*5 + 1];
    float Y  = RayInit[ray*5 + 2];
    float dY = RayInit[ray*5 + 3];
    float z  = RayInit[ray*5 + 4];

    if (nb == 0) { lX[0][rl] = X*2.0f - 1.0f; lY[0][rl] = Y*2.0f - 1.0f; }

    auto prep = [&](float pX, float pY, float pz,
                    float& ox, float& oy, float& oz,
                    float& X1, float& Y1, float& Z1,
                    float& X2, float& Y2, float& Z2,
                    float2& r1, float2& r2) {
        float x  = pY*M.crd[1] + pX*M.crd[5] + pz*M.crd[9]  + M.crd[13];
        float y  = pY*M.crd[0] + pX*M.crd[4] + pz*M.crd[8]  + M.crd[12];
        float zz = pY*M.crd[2] + pX*M.crd[6] + pz*M.crd[10] + M.crd[14];
        float rx_ = rintf(x*64.0f), ry_ = rintf(y*64.0f), rz_ = rintf(zz*64.0f);
        X1 = __builtin_amdgcn_fmed3f(rx_ + xr1, 0.0f, 63.0f);
        Y1 = __builtin_amdgcn_fmed3f(ry_ + yr1, 0.0f, 63.0f);
        Z1 = __builtin_amdgcn_fmed3f(rz_ + zr1, 0.0f, 63.0f);
        X2 = __builtin_amdgcn_fmed3f(rx_ + xr2, 0.0f, 63.0f);
        Y2 = __builtin_amdgcn_fmed3f(ry_ + yr2, 0.0f, 63.0f);
        Z2 = __builtin_amdgcn_fmed3f(rz_ + zr2, 0.0f, 63.0f);
        int l1 = (int)(Y1*4096.0f + X1*64.0f + Z1);   // exact in fp32
        int l2 = (int)(Y2*4096.0f + X2*64.0f + Z2);
        r1 = ((const float2*)RI)[l1];
        r2 = ((const float2*)RI)[l2];
        ox = x; oy = y; oz = zz;
    };

    float cx_, cy_, cz_, Xn1, Yn1, Zn1, Xn2, Yn2, Zn2;
    float2 ri1, ri2;
    prep(X, Y, z, cx_, cy_, cz_, Xn1, Yn1, Zn1, Xn2, Yn2, Zn2, ri1, ri2);

    // v_exp_f32 computes 2^x: fold -0.5*log2(e) into the Gaussian constant.
    const float C = -0.72134752044448169f;   // -0.5 * log2(e)

    #pragma unroll 7
    for (int s = 1; s < NSAMP; ++s) {
        // one-step-ahead prefetch (uses only pre-reduction state)
        float nX = X + dX*STEP, nY = Y + dY*STEP, nz = z + STEP;
        float ncx, ncy, ncz, mX1, mY1, mZ1, mX2, mY2, mZ2;
        float2 ri1n, ri2n;
        prep(nX, nY, nz, ncx, ncy, ncz, mX1, mY1, mZ1, mX2, mY2, mZ2, ri1n, ri2n);

        // neighbor 1 contribution
        float dx1 = Xn1*(1.0f/63.0f) - cx_;
        float dy1 = Yn1*(1.0f/63.0f) - cy_;
        float dz1 = Zn1*(1.0f/63.0f) - cz_;
        float is1 = __builtin_amdgcn_rcpf(ri1.y * ri1.y);
        float d21 = dx1*dx1 + dy1*dy1 + dz1*dz1;
        float e1  = __builtin_amdgcn_exp2f(d21 * is1 * C) + 2e-7f;
        float g1x = dx1*is1, g1y = dy1*is1, g1z = dz1*is1;
        float nu1 = e1 * ri1.x;

        // neighbor 2 contribution (zeroed when inactive)
        float dx2 = Xn2*(1.0f/63.0f) - cx_;
        float dy2 = Yn2*(1.0f/63.0f) - cy_;
        float dz2 = Zn2*(1.0f/63.0f) - cz_;
        float is2 = __builtin_amdgcn_rcpf(ri2.y * ri2.y);
        float d22 = dx2*dx2 + dy2*dy2 + dz2*dz2;
        float e2  = __builtin_amdgcn_exp2f(d22 * is2 * C) + 2e-7f;
        if (!act2) e2 = 0.0f;
        float g2x = dx2*is2, g2y = dy2*is2, g2z = dz2*is2;
        float nu2 = e2 * ri2.x;

        float v[8] = { e1 + e2,
                       nu1 + nu2,
                       nu1*g1x + nu2*g2x,
                       nu1*g1y + nu2*g2y,
                       nu1*g1z + nu2*g2z,
                       e1*g1x + e2*g2x,
                       e1*g1y + e2*g2y,
                       e1*g1z + e2*g2z };
        red8_16(v);
        float ni  = v[0], nuA = v[1];
        float sx  = v[2], sy  = v[3], sz  = v[4];
        float sdx = v[5], sdy = v[6], sdz = v[7];

        float r   = __builtin_amdgcn_rcpf(ni);
        float rn  = ni * __builtin_amdgcn_rcpf(nuA);   // 1/n = norm/nu_s
        float in2 = r * r;
        float gx_ = (ni*sx - nuA*sdx) * in2;
        float gy_ = (ni*sy - nuA*sdy) * in2;
        float gz_ = (ni*sz - nuA*sdz) * in2;

        float dndx = gy_*M.drv[1] + gx_*M.drv[5] + gz_*M.drv[9]  + M.drv[13];
        float dndy = gy_*M.drv[0] + gx_*M.drv[4] + gz_*M.drv[8]  + M.drv[12];
        float dndz = gy_*M.drv[2] + gx_*M.drv[6] + gz_*M.drv[10] + M.drv[14];

        float dX2 = (dndx - dndz*dX) * (1.0f + dX*dX) * rn;
        float dY2 = (dndy - dndz*dY) * (1.0f + dY*dY) * rn;

        X = nX; Y = nY; z = nz;
        dX += dX2 * STEP;
        dY += dY2 * STEP;

        // LDS buffer instead of global store: keeps vmcnt queue loads-only
        if (nb == 0) { lX[s][rl] = X*2.0f - 1.0f; lY[s][rl] = Y*2.0f - 1.0f; }

        cx_ = ncx; cy_ = ncy; cz_ = ncz;
        Xn1 = mX1; Yn1 = mY1; Zn1 = mZ1;
        Xn2 = mX2; Yn2 = mY2; Zn2 = mZ2;
        ri1 = ri1n; ri2 = ri2n;
    }

    __syncthreads();   // single wave: cheap; orders ds_writes before reads

    // bulk writeout: lane s stores this block's 4 rays as one float4 per array
    {
        const int s = tid;                     // 0..63
        const int ray0 = blockIdx.x * 4;
        float4 vx = *(const float4*)&lX[s][0];
        float4 vy = *(const float4*)&lY[s][0];
        *(float4*)&meshXT[s*NRAY2 + ray0] = vx;
        *(float4*)&meshYT[s*NRAY2 + ray0] = vy;
    }
}

// ---------------- kernel 2: fused resize + grid sample ----------------------
// Pack-of-4 version (unchanged from R8).
typedef _Float16 h16;
typedef _Float16 h16v4 __attribute__((ext_vector_type(4)));

__global__ __launch_bounds__(1024) void sample_kernel(
    const float* __restrict__ vol,      // 192^3
    const float* __restrict__ meshXT,   // (64, 4096)
    const float* __restrict__ meshYT,
    h16*   __restrict__ outTh,          // fp16 transposed out [c][a*192+b]
    float* __restrict__ outDirect,      // fallback fp32 out [a][b][c]
    int transposed)
{
    __shared__ h16    plane_h[PLANE];     // 73,728 B
    __shared__ float2 slice[64*64];       // 32,768 B

    const int tid = threadIdx.x;
    const int blk = blockIdx.x;
    const int c = (blk >> 3) + 24 * (blk & 7);   // consecutive c on same XCD

    const float D = 63.0f / 191.0f;

    {
        const float4* src = (const float4*)(vol + c * PLANE);
        h16v4* dst = (h16v4*)plane_h;
        #pragma unroll
        for (int k = 0; k < (PLANE/4)/1024; ++k) {
            float4 v = src[tid + k*1024];
            h16v4 hv = {(h16)v.x, (h16)v.y, (h16)v.z, (h16)v.w};
            dst[tid + k*1024] = hv;
        }
    }

    float ps = c * D;
    int s0 = min((int)ps, 62);
    float wcs = ps - (float)s0, wc0 = 1.0f - wcs;
    {
        const float* x0 = meshXT + s0*NRAY2;
        const float* x1 = meshXT + (s0+1)*NRAY2;
        const float* y0 = meshYT + s0*NRAY2;
        const float* y1 = meshYT + (s0+1)*NRAY2;
        #pragma unroll
        for (int k = 0; k < 4096/1024; ++k) {
            int t = tid + k*1024;
            slice[t] = make_float2(x0[t]*wc0 + x1[t]*wcs,
                                   y0[t]*wc0 + y1[t]*wcs);
        }
    }
    __syncthreads();

    #pragma unroll 1
    for (int k = 0; k < PLANE/4096; ++k) {        // 9 iterations
        const int w0 = (tid + k*1024) * 4;        // linear within plane
        const int a  = w0 / PHD;                  // pack stays in one row
        const int b0 = w0 - a*PHD;

        float pa = (float)a * D;
        int   i0 = min((int)pa, 62);
        float wa = pa - (float)i0;

        float pb0 = (float)b0 * D;
        int  jmin = min((int)pb0, 62);
        int  j2   = min(jmin + 2, 63);

        float2 r0c0 = slice[i0*64 + jmin];
        float2 r0c1 = slice[i0*64 + jmin + 1];
        float2 r0c2 = slice[i0*64 + j2];
        float2 r1c0 = slice[(i0+1)*64 + jmin];
        float2 r1c1 = slice[(i0+1)*64 + jmin + 1];
        float2 r1c2 = slice[(i0+1)*64 + j2];

        float c0x = r0c0.x + wa*(r1c0.x - r0c0.x);
        float c0y = r0c0.y + wa*(r1c0.y - r0c0.y);
        float c1x = r0c1.x + wa*(r1c1.x - r0c1.x);
        float c1y = r0c1.y + wa*(r1c1.y - r0c1.y);
        float c2x = r0c2.x + wa*(r1c2.x - r0c2.x);
        float c2y = r0c2.y + wa*(r1c2.y - r0c2.y);

        h16v4 res;
        #pragma unroll
        for (int m = 0; m < 4; ++m) {
            float pb = (float)(b0 + m) * D;
            int   j0 = min((int)pb, 62);
            float wb = pb - (float)j0;
            bool  hi = (j0 != jmin);

            float sax = hi ? c1x : c0x, say = hi ? c1y : c0y;
            float sbx = hi ? c2x : c1x, sby = hi ? c2y : c1y;
            float gx = sax + wb*(sbx - sax);
            float gy = say + wb*(sby - say);

            float ix = (gx + 1.0f) * 0.5f * 191.0f;
            float iy = (gy + 1.0f) * 0.5f * 191.0f;
            float x0f = floorf(ix); float fx = ix - x0f;
            float y0f = floorf(iy); float fy = iy - y0f;

            float acc = 0.0f;
            #pragma unroll
            for (int dyy = 0; dyy < 2; ++dyy) {
                #pragma unroll
                for (int dxx = 0; dxx < 2; ++dxx) {
                    float xi = x0f + (float)dxx;
                    float yi = y0f + (float)dyy;
                    bool inb = (xi >= 0.0f) && (xi <= 191.0f) &&
                               (yi >= 0.0f) && (yi <= 191.0f);
                    int xc = min(max((int)xi, 0), PHD - 1);
                    int yc = min(max((int)yi, 0), PHD - 1);
                    float w = (dxx ? fx : 1.0f - fx) * (dyy ? fy : 1.0f - fy);
                    float val = (float)plane_h[yc*PHD + xc];
                    acc += inb ? w * val : 0.0f;
                }
            }
            res[m] = (h16)acc;
        }

        if (transposed) {
            *(h16v4*)(outTh + (size_t)c*PLANE + w0) = res;   // 8 B contiguous
        } else {
            #pragma unroll
            for (int m = 0; m < 4; ++m)
                outDirect[(size_t)(a*PHD + b0 + m)*PHD + c] = (float)res[m];
        }
    }
}

// ---------------- kernel 3: (b,c) tile transpose, fp16 -> fp32 --------------
__global__ __launch_bounds__(256) void transpose_kernel(
    const h16* __restrict__ outTh, float* __restrict__ out)
{
    __shared__ h16 t[64][66];
    const int a  = blockIdx.z;
    const int b0 = blockIdx.x * 64;
    const int c0 = blockIdx.y * 64;
    const int tx = threadIdx.x & 63;
    const int ty = threadIdx.x >> 6;     // 0..3

    const h16* src = outTh + (size_t)(c0 + ty) * PLANE + a*PHD + b0 + tx;
    #pragma unroll
    for (int j = 0; j < 16; ++j)
        t[ty + 4*j][tx] = src[(size_t)(4*j) * PLANE];
    __syncthreads();

    float* dst = out + (size_t)a * PLANE + (size_t)(b0 + ty) * PHD + c0 + tx;
    #pragma unroll
    for (int j = 0; j < 16; ++j)
        dst[(size_t)(4*j) * PHD] = (float)t[tx][ty + 4*j];
}

// ---------------- launch -----------------------------------------------------
extern "C" void kernel_launch(void* const* d_in, const int* in_sizes, int n_in,
                              void* d_out, int out_size, void* d_ws, size_t ws_size,
                              hipStream_t stream)
{
    const float* Phantom = (const float*)d_in[0];   // 192^3
    const float* RI      = (const float*)d_in[1];   // (64^3, 2)
    const float* RayInit = (const float*)d_in[2];   // (4096, 5)
    float* out = (float*)d_out;

    float* meshXT = (float*)d_ws;                   // (64, 4096)   1 MB
    float* meshYT = meshXT + NRAY2 * NSAMP;         // (64, 4096)   1 MB
    h16*   outTh  = (h16*)(meshYT + NRAY2 * NSAMP); // 192^3 fp16   14.2 MB

    const size_t need = (size_t)(2 * NRAY2 * NSAMP) * sizeof(float)
                      + (size_t)PHD * PLANE * sizeof(h16);
    const int use_transpose = (ws_size >= need) ? 1 : 0;

    Mats M;
    build_mats(M);

    ray_trace_kernel<<<NRAY2/4, 64, 0, stream>>>(RI, RayInit, meshXT, meshYT, M);

    if (use_transpose) {
        sample_kernel<<<PHD, 1024, 0, stream>>>(Phantom, meshXT, meshYT,
                                                outTh, nullptr, 1);
        transpose_kernel<<<dim3(3, 3, PHD), 256, 0, stream>>>(outTh, out);
    } else {
        sample_kernel<<<PHD, 1024, 0, stream>>>(Phantom, meshXT, meshYT,
                                                nullptr, out, 0);
    }
}